// Round 2
// baseline (234.076 us; speedup 1.0000x reference)
//
#include <hip/hip_runtime.h>

// Segment-mean pool: x [N][128] f32, batch [N] int (sorted, values in [0,16)),
// out [16][128] f32 = segment_sum(x)/max(count,1).

#define D       128
#define D4      32          // D/4 float4 per row
#define BSEG    16
#define THREADS 256
#define ROWS_PER_ITER 8     // THREADS / D4

__global__ __launch_bounds__(THREADS) void pool_sum_kernel(
    const float* __restrict__ x,
    const int*   __restrict__ batch,
    float*       __restrict__ sums,    // [BSEG*D] global accumulator (zeroed)
    float*       __restrict__ counts,  // [BSEG]   global accumulator (zeroed)
    int N, int nblocks)
{
    __shared__ float lds_sum[BSEG][D];
    __shared__ float lds_cnt[BSEG];

    const int tid = threadIdx.x;

    // zero the block-local accumulators
    for (int i = tid; i < BSEG * D; i += THREADS) ((float*)lds_sum)[i] = 0.0f;
    if (tid < BSEG) lds_cnt[tid] = 0.0f;
    __syncthreads();

    // contiguous row chunk per block (exploits sortedness of batch)
    const long chunk = ((long)N + nblocks - 1) / nblocks;
    const long r0 = (long)blockIdx.x * chunk;
    long r1 = r0 + chunk;
    if (r1 > (long)N) r1 = (long)N;
    if (r0 >= r1) return;

    const int col4  = tid & (D4 - 1);   // which float4 of the row
    const int rlane = tid >> 5;         // 0..7: row offset within iteration

    const float4* __restrict__ x4 = (const float4*)x;

    const int seg_lo = batch[r0];
    const int seg_hi = batch[r1 - 1];

    if (seg_lo == seg_hi) {
        // ---- fast path (99.3% of blocks): single segment, no batch loads,
        // branch-free inner loop -> compiler unrolls, many loads in flight.
        float4 acc = make_float4(0.f, 0.f, 0.f, 0.f);
        #pragma unroll 4
        for (long r = r0 + rlane; r < r1; r += ROWS_PER_ITER) {
            float4 v = x4[r * D4 + col4];
            acc.x += v.x; acc.y += v.y; acc.z += v.z; acc.w += v.w;
        }
        atomicAdd(&lds_sum[seg_lo][col4 * 4 + 0], acc.x);
        atomicAdd(&lds_sum[seg_lo][col4 * 4 + 1], acc.y);
        atomicAdd(&lds_sum[seg_lo][col4 * 4 + 2], acc.z);
        atomicAdd(&lds_sum[seg_lo][col4 * 4 + 3], acc.w);
        if (tid == 0) lds_cnt[seg_lo] = (float)(r1 - r0);
    } else {
        // ---- slow path: segment boundary inside this chunk.
        float4 acc = make_float4(0.f, 0.f, 0.f, 0.f);
        int    cnt = 0;
        int    cur = -1;

        for (long r = r0 + rlane; r < r1; r += ROWS_PER_ITER) {
            int seg = batch[r];
            if (seg != cur) {
                if (cur >= 0) {
                    atomicAdd(&lds_sum[cur][col4 * 4 + 0], acc.x);
                    atomicAdd(&lds_sum[cur][col4 * 4 + 1], acc.y);
                    atomicAdd(&lds_sum[cur][col4 * 4 + 2], acc.z);
                    atomicAdd(&lds_sum[cur][col4 * 4 + 3], acc.w);
                    if (col4 == 0) atomicAdd(&lds_cnt[cur], (float)cnt);
                }
                acc = make_float4(0.f, 0.f, 0.f, 0.f);
                cnt = 0;
                cur = (seg >= 0 && seg < BSEG) ? seg : -1;
            }
            if (cur >= 0) {
                float4 v = x4[r * D4 + col4];
                acc.x += v.x; acc.y += v.y; acc.z += v.z; acc.w += v.w;
                cnt++;
            }
        }
        if (cur >= 0) {
            atomicAdd(&lds_sum[cur][col4 * 4 + 0], acc.x);
            atomicAdd(&lds_sum[cur][col4 * 4 + 1], acc.y);
            atomicAdd(&lds_sum[cur][col4 * 4 + 2], acc.z);
            atomicAdd(&lds_sum[cur][col4 * 4 + 3], acc.w);
            if (col4 == 0) atomicAdd(&lds_cnt[cur], (float)cnt);
        }
    }
    __syncthreads();

    // one global flush per block; skip zeros to cut atomic traffic
    for (int i = tid; i < BSEG * D; i += THREADS) {
        float v = ((float*)lds_sum)[i];
        if (v != 0.0f) atomicAdd(&sums[i], v);
    }
    if (tid < BSEG) {
        float c = lds_cnt[tid];
        if (c != 0.0f) atomicAdd(&counts[tid], c);
    }
}

__global__ __launch_bounds__(THREADS) void pool_div_kernel(
    const float* __restrict__ sums,
    const float* __restrict__ counts,
    float*       __restrict__ out)
{
    int i = blockIdx.x * THREADS + threadIdx.x;
    if (i < BSEG * D) {
        float c = counts[i / D];
        out[i] = sums[i] / fmaxf(c, 1.0f);
    }
}

extern "C" void kernel_launch(void* const* d_in, const int* in_sizes, int n_in,
                              void* d_out, int out_size, void* d_ws, size_t ws_size,
                              hipStream_t stream)
{
    const float* x     = (const float*)d_in[0];
    const int*   batch = (const int*)d_in[1];
    const int    N     = in_sizes[1];          // one id per row

    float* sums   = (float*)d_ws;              // [BSEG*D]
    float* counts = sums + BSEG * D;           // [BSEG]

    hipMemsetAsync(d_ws, 0, (BSEG * D + BSEG) * sizeof(float), stream);

    const int nblocks = 2048;
    pool_sum_kernel<<<nblocks, THREADS, 0, stream>>>(x, batch, sums, counts, N, nblocks);

    pool_div_kernel<<<(BSEG * D + THREADS - 1) / THREADS, THREADS, 0, stream>>>(
        sums, counts, (float*)d_out);
}

// Round 3
// 228.539 us; speedup vs baseline: 1.0242x; 1.0242x over previous
//
#include <hip/hip_runtime.h>

// Segment-mean pool: x [N][128] f32, batch [N] int (sorted, values in [0,16)),
// out [16][128] f32 = segment_sum(x)/max(count,1).

#define D       128
#define D4      32          // D/4 float4 per row
#define BSEG    16
#define THREADS 256
#define ROWS_PER_ITER 8     // THREADS / D4

__global__ __launch_bounds__(THREADS) void pool_sum_kernel(
    const float* __restrict__ x,
    const int*   __restrict__ batch,
    float*       __restrict__ sums,    // [BSEG*D] global accumulator (zeroed)
    float*       __restrict__ counts,  // [BSEG]   global accumulator (zeroed)
    int N, int nblocks)
{
    __shared__ float lds_sum[BSEG][D];
    __shared__ float lds_cnt[BSEG];

    const int tid = threadIdx.x;

    for (int i = tid; i < BSEG * D; i += THREADS) ((float*)lds_sum)[i] = 0.0f;
    if (tid < BSEG) lds_cnt[tid] = 0.0f;
    __syncthreads();

    // contiguous row chunk per block (exploits sortedness of batch)
    const int chunk = (N + nblocks - 1) / nblocks;
    const int r0 = blockIdx.x * chunk;
    int r1 = r0 + chunk;
    if (r1 > N) r1 = N;
    if (r0 >= r1) return;

    const int col4 = tid & (D4 - 1);    // constant column: tid & 31

    const float4* __restrict__ x4 = (const float4*)x;

    const int seg_lo = batch[r0];
    const int seg_hi = batch[r1 - 1];

    if (seg_lo == seg_hi) {
        // ---- fast path (~99.3% of blocks): single segment.
        // Flat float4 iteration; stride 256 keeps column = tid&31 constant.
        // 4 independent accumulators -> 4 loads in flight, no dep chain.
        const float4* __restrict__ p = x4 + (long)r0 * D4;
        const int n4 = (r1 - r0) * D4;           // ~31264 float4s

        float4 a0 = make_float4(0.f, 0.f, 0.f, 0.f);
        float4 a1 = a0, a2 = a0, a3 = a0;

        int i = tid;
        for (; i + 3 * THREADS < n4; i += 4 * THREADS) {
            float4 v0 = p[i];
            float4 v1 = p[i +     THREADS];
            float4 v2 = p[i + 2 * THREADS];
            float4 v3 = p[i + 3 * THREADS];
            a0.x += v0.x; a0.y += v0.y; a0.z += v0.z; a0.w += v0.w;
            a1.x += v1.x; a1.y += v1.y; a1.z += v1.z; a1.w += v1.w;
            a2.x += v2.x; a2.y += v2.y; a2.z += v2.z; a2.w += v2.w;
            a3.x += v3.x; a3.y += v3.y; a3.z += v3.z; a3.w += v3.w;
        }
        for (; i < n4; i += THREADS) {
            float4 v = p[i];
            a0.x += v.x; a0.y += v.y; a0.z += v.z; a0.w += v.w;
        }
        float4 acc;
        acc.x = (a0.x + a1.x) + (a2.x + a3.x);
        acc.y = (a0.y + a1.y) + (a2.y + a3.y);
        acc.z = (a0.z + a1.z) + (a2.z + a3.z);
        acc.w = (a0.w + a1.w) + (a2.w + a3.w);

        atomicAdd(&lds_sum[seg_lo][col4 * 4 + 0], acc.x);
        atomicAdd(&lds_sum[seg_lo][col4 * 4 + 1], acc.y);
        atomicAdd(&lds_sum[seg_lo][col4 * 4 + 2], acc.z);
        atomicAdd(&lds_sum[seg_lo][col4 * 4 + 3], acc.w);
        if (tid == 0) lds_cnt[seg_lo] = (float)(r1 - r0);
    } else {
        // ---- slow path: segment boundary inside this chunk (~15 blocks).
        const int rlane = tid >> 5;     // 0..7
        float4 acc = make_float4(0.f, 0.f, 0.f, 0.f);
        int    cnt = 0;
        int    cur = -1;

        for (int r = r0 + rlane; r < r1; r += ROWS_PER_ITER) {
            int seg = batch[r];
            if (seg != cur) {
                if (cur >= 0) {
                    atomicAdd(&lds_sum[cur][col4 * 4 + 0], acc.x);
                    atomicAdd(&lds_sum[cur][col4 * 4 + 1], acc.y);
                    atomicAdd(&lds_sum[cur][col4 * 4 + 2], acc.z);
                    atomicAdd(&lds_sum[cur][col4 * 4 + 3], acc.w);
                    if (col4 == 0) atomicAdd(&lds_cnt[cur], (float)cnt);
                }
                acc = make_float4(0.f, 0.f, 0.f, 0.f);
                cnt = 0;
                cur = (seg >= 0 && seg < BSEG) ? seg : -1;
            }
            if (cur >= 0) {
                float4 v = x4[(long)r * D4 + col4];
                acc.x += v.x; acc.y += v.y; acc.z += v.z; acc.w += v.w;
                cnt++;
            }
        }
        if (cur >= 0) {
            atomicAdd(&lds_sum[cur][col4 * 4 + 0], acc.x);
            atomicAdd(&lds_sum[cur][col4 * 4 + 1], acc.y);
            atomicAdd(&lds_sum[cur][col4 * 4 + 2], acc.z);
            atomicAdd(&lds_sum[cur][col4 * 4 + 3], acc.w);
            if (col4 == 0) atomicAdd(&lds_cnt[cur], (float)cnt);
        }
    }
    __syncthreads();

    // one global flush per block; skip zeros to cut atomic traffic
    for (int i = tid; i < BSEG * D; i += THREADS) {
        float v = ((float*)lds_sum)[i];
        if (v != 0.0f) atomicAdd(&sums[i], v);
    }
    if (tid < BSEG) {
        float c = lds_cnt[tid];
        if (c != 0.0f) atomicAdd(&counts[tid], c);
    }
}

__global__ __launch_bounds__(THREADS) void pool_div_kernel(
    const float* __restrict__ sums,
    const float* __restrict__ counts,
    float*       __restrict__ out)
{
    int i = blockIdx.x * THREADS + threadIdx.x;
    if (i < BSEG * D) {
        float c = counts[i / D];
        out[i] = sums[i] / fmaxf(c, 1.0f);
    }
}

extern "C" void kernel_launch(void* const* d_in, const int* in_sizes, int n_in,
                              void* d_out, int out_size, void* d_ws, size_t ws_size,
                              hipStream_t stream)
{
    const float* x     = (const float*)d_in[0];
    const int*   batch = (const int*)d_in[1];
    const int    N     = in_sizes[1];          // one id per row

    float* sums   = (float*)d_ws;              // [BSEG*D]
    float* counts = sums + BSEG * D;           // [BSEG]

    hipMemsetAsync(d_ws, 0, (BSEG * D + BSEG) * sizeof(float), stream);

    const int nblocks = 2048;
    pool_sum_kernel<<<nblocks, THREADS, 0, stream>>>(x, batch, sums, counts, N, nblocks);

    pool_div_kernel<<<(BSEG * D + THREADS - 1) / THREADS, THREADS, 0, stream>>>(
        sums, counts, (float*)d_out);
}

// Round 4
// 200.908 us; speedup vs baseline: 1.1651x; 1.1375x over previous
//
#include <hip/hip_runtime.h>

// Segment-mean pool: x [N][128] f32, batch [N] int32 (sorted, 0..15),
// out [16][128] f32 = segment_sum(x)/max(count,1).
//
// Strategy: segment-partitioned GPU-wide linear streaming.
//   k1: find 17 segment boundary offsets from sorted batch.
//   k2: for each segment, ALL threads grid-stride linearly over its
//       contiguous float4 range (compact moving address window, like the
//       6.4 TB/s fill kernels) -> block partials, no global atomics.
//   k3: reduce block partials.  k4: divide by counts (boundary diffs).

#define D       128
#define D4      32
#define BSEG    16
#define BD      (BSEG * D)          // 2048

#define MB_BLOCKS   512
#define MB_THREADS  512
#define GSTRIDE     (MB_BLOCKS * MB_THREADS)   // 262144 float4s, ≡0 mod 32

// ---- k1: boundaries. start[s] = first row of segment s; start[16] = N.
__global__ __launch_bounds__(256)
void boundary_kernel(const int* __restrict__ batch, int N, int* __restrict__ start)
{
    int stride = gridDim.x * 256;
    for (int i = blockIdx.x * 256 + threadIdx.x; i < N; i += stride) {
        int b = batch[i]; b = min(max(b, 0), BSEG - 1);
        if (i == 0)
            for (int s = 0; s <= b; ++s) start[s] = 0;
        if (i + 1 < N) {
            int c = batch[i + 1]; c = min(max(c, 0), BSEG - 1);
            for (int s = b + 1; s <= c; ++s) start[s] = i + 1;
        } else {
            for (int s = b + 1; s <= BSEG; ++s) start[s] = N;
        }
    }
}

// ---- k2: main streaming sum.
__global__ __launch_bounds__(MB_THREADS)
void pool_main(const float4* __restrict__ x4, const int* __restrict__ start,
               float* __restrict__ partial /* [MB_BLOCKS][BD] */)
{
    __shared__ float lds_sum[BSEG][D];
    const int tid = threadIdx.x;
    for (int i = tid; i < BD; i += MB_THREADS) ((float*)lds_sum)[i] = 0.0f;
    __syncthreads();

    const int gtid = blockIdx.x * MB_THREADS + tid;
    const int col4 = tid & (D4 - 1);      // constant column (stride ≡ 0 mod 32)
    const int lane = tid & 63;

    int st[BSEG + 1];
    #pragma unroll
    for (int s = 0; s <= BSEG; ++s) st[s] = start[s];

    #pragma unroll 1
    for (int s = 0; s < BSEG; ++s) {
        const int e1 = st[s + 1] * D4;          // max 64M, fits int
        float4 a = make_float4(0.f, 0.f, 0.f, 0.f);
        for (int i = st[s] * D4 + gtid; i < e1; i += GSTRIDE) {
            float4 v = x4[i];
            a.x += v.x; a.y += v.y; a.z += v.z; a.w += v.w;
        }
        // lanes l and l+32 hold the same column: fold within wave
        a.x += __shfl_down(a.x, 32);
        a.y += __shfl_down(a.y, 32);
        a.z += __shfl_down(a.z, 32);
        a.w += __shfl_down(a.w, 32);
        if (lane < 32) {
            atomicAdd(&lds_sum[s][col4 * 4 + 0], a.x);
            atomicAdd(&lds_sum[s][col4 * 4 + 1], a.y);
            atomicAdd(&lds_sum[s][col4 * 4 + 2], a.z);
            atomicAdd(&lds_sum[s][col4 * 4 + 3], a.w);
        }
    }
    __syncthreads();

    // BD/4 == 512 == MB_THREADS: exactly one float4 store per thread
    float4* pp = (float4*)(partial + (long)blockIdx.x * BD);
    pp[tid] = ((const float4*)lds_sum)[tid];
}

// ---- k3: reduce partials.  32768 threads = 2048 cols x 16 row-groups.
__global__ __launch_bounds__(256)
void stage2_kernel(const float* __restrict__ partial, float* __restrict__ sums)
{
    int g   = blockIdx.x * 256 + threadIdx.x;   // 0..32767
    int col = g & (BD - 1);
    int grp = g >> 11;                          // 0..15
    const int rows = MB_BLOCKS / 16;            // 32
    int r0 = grp * rows;
    float s = 0.f;
    for (int k = 0; k < rows; ++k)
        s += partial[(r0 + k) * BD + col];
    atomicAdd(&sums[col], s);
}

// ---- k4: divide by counts derived from boundaries.
__global__ __launch_bounds__(256)
void div_kernel(const float* __restrict__ sums, const int* __restrict__ start,
                float* __restrict__ out)
{
    int i = blockIdx.x * 256 + threadIdx.x;
    if (i < BD) {
        int s = i >> 7;
        float c = (float)(start[s + 1] - start[s]);
        out[i] = sums[i] / fmaxf(c, 1.0f);
    }
}

// ---------------- fallback (round-1 kernel) if ws is too small --------------
__global__ __launch_bounds__(256)
void pool_sum_fb(const float* __restrict__ x, const int* __restrict__ batch,
                 float* __restrict__ sums, float* __restrict__ counts,
                 int N, int nblocks)
{
    __shared__ float lds_sum[BSEG][D];
    __shared__ float lds_cnt[BSEG];
    const int tid = threadIdx.x;
    for (int i = tid; i < BD; i += 256) ((float*)lds_sum)[i] = 0.0f;
    if (tid < BSEG) lds_cnt[tid] = 0.0f;
    __syncthreads();

    const int chunk = (N + nblocks - 1) / nblocks;
    const int r0 = blockIdx.x * chunk;
    int r1 = r0 + chunk; if (r1 > N) r1 = N;
    const int col4 = tid & (D4 - 1);
    const int rlane = tid >> 5;
    const float4* x4 = (const float4*)x;

    float4 acc = make_float4(0.f, 0.f, 0.f, 0.f);
    int cnt = 0, cur = -1;
    for (int r = r0 + rlane; r < r1; r += 8) {
        int seg = batch[r];
        if (seg != cur) {
            if (cur >= 0) {
                atomicAdd(&lds_sum[cur][col4 * 4 + 0], acc.x);
                atomicAdd(&lds_sum[cur][col4 * 4 + 1], acc.y);
                atomicAdd(&lds_sum[cur][col4 * 4 + 2], acc.z);
                atomicAdd(&lds_sum[cur][col4 * 4 + 3], acc.w);
                if (col4 == 0) atomicAdd(&lds_cnt[cur], (float)cnt);
            }
            acc = make_float4(0.f, 0.f, 0.f, 0.f); cnt = 0;
            cur = (seg >= 0 && seg < BSEG) ? seg : -1;
        }
        if (cur >= 0) {
            float4 v = x4[(long)r * D4 + col4];
            acc.x += v.x; acc.y += v.y; acc.z += v.z; acc.w += v.w; cnt++;
        }
    }
    if (cur >= 0) {
        atomicAdd(&lds_sum[cur][col4 * 4 + 0], acc.x);
        atomicAdd(&lds_sum[cur][col4 * 4 + 1], acc.y);
        atomicAdd(&lds_sum[cur][col4 * 4 + 2], acc.z);
        atomicAdd(&lds_sum[cur][col4 * 4 + 3], acc.w);
        if (col4 == 0) atomicAdd(&lds_cnt[cur], (float)cnt);
    }
    __syncthreads();
    for (int i = tid; i < BD; i += 256) {
        float v = ((float*)lds_sum)[i];
        if (v != 0.0f) atomicAdd(&sums[i], v);
    }
    if (tid < BSEG) {
        float c = lds_cnt[tid];
        if (c != 0.0f) atomicAdd(&counts[tid], c);
    }
}

__global__ __launch_bounds__(256)
void div_fb(const float* __restrict__ sums, const float* __restrict__ counts,
            float* __restrict__ out)
{
    int i = blockIdx.x * 256 + threadIdx.x;
    if (i < BD) out[i] = sums[i] / fmaxf(counts[i >> 7], 1.0f);
}

// ---------------------------------------------------------------------------
extern "C" void kernel_launch(void* const* d_in, const int* in_sizes, int n_in,
                              void* d_out, int out_size, void* d_ws, size_t ws_size,
                              hipStream_t stream)
{
    const float* x     = (const float*)d_in[0];
    const int*   batch = (const int*)d_in[1];
    const int    N     = in_sizes[1];

    // ws layout: [start: 32 ints][sums: BD floats][partial: MB_BLOCKS*BD floats]
    int*   start   = (int*)d_ws;
    float* sums    = (float*)d_ws + 32;
    float* partial = (float*)d_ws + 32 + BD;
    const size_t need = (size_t)(32 + BD + (size_t)MB_BLOCKS * BD) * sizeof(float);

    if (ws_size >= need) {
        hipMemsetAsync(sums, 0, BD * sizeof(float), stream);
        boundary_kernel<<<2048, 256, 0, stream>>>(batch, N, start);
        pool_main<<<MB_BLOCKS, MB_THREADS, 0, stream>>>((const float4*)x, start, partial);
        stage2_kernel<<<128, 256, 0, stream>>>(partial, sums);
        div_kernel<<<8, 256, 0, stream>>>(sums, start, (float*)d_out);
    } else {
        float* fsums   = (float*)d_ws;
        float* fcounts = fsums + BD;
        hipMemsetAsync(d_ws, 0, (BD + BSEG) * sizeof(float), stream);
        pool_sum_fb<<<2048, 256, 0, stream>>>(x, batch, fsums, fcounts, N, 2048);
        div_fb<<<8, 256, 0, stream>>>(fsums, fcounts, (float*)d_out);
    }
}

// Round 5
// 193.890 us; speedup vs baseline: 1.2073x; 1.0362x over previous
//
#include <hip/hip_runtime.h>

// Segment-mean pool: x [N][128] f32, batch [N] int32 (sorted, 0..15),
// out [16][128] f32 = segment_sum(x)/max(count,1).
//
// Strategy: segment-partitioned GPU-wide linear streaming at FULL occupancy.
//   k1: boundary offsets from sorted batch (int4 scan).
//   k2: per segment, all 524288 threads grid-stride linearly over its
//       contiguous float4 range -> block partials (no global atomics).
//       1024 thr/block, __launch_bounds__(1024,8) => <=64 VGPR => 32 waves/CU.
//   k3: reduce block partials.  k4: divide by counts (boundary diffs).

#define D       128
#define D4      32
#define BSEG    16
#define BD      (BSEG * D)          // 2048

#define MB_BLOCKS   512
#define MB_THREADS  1024
#define GSTRIDE     (MB_BLOCKS * MB_THREADS)   // 524288 float4s, ≡0 mod 32

// ---- k1: boundaries. start[s] = first row of segment s; start[16] = N.
__global__ __launch_bounds__(256)
void boundary_kernel(const int* __restrict__ batch, int N, int* __restrict__ start)
{
    int t  = blockIdx.x * 256 + threadIdx.x;
    int i0 = t * 4;
    if (i0 >= N) return;

    int e[5];
    if (i0 + 4 <= N) {
        int4 b = *(const int4*)(batch + i0);
        e[0] = b.x; e[1] = b.y; e[2] = b.z; e[3] = b.w;
    } else {
        for (int k = 0; k < 4; ++k) e[k] = (i0 + k < N) ? batch[i0 + k] : batch[N - 1];
    }
    bool last = (i0 + 4 >= N);
    e[4] = last ? BSEG : batch[i0 + 4];

    if (i0 == 0) {
        int b0 = min(max(e[0], 0), BSEG - 1);
        for (int s = 0; s <= b0; ++s) start[s] = 0;
    }
    for (int k = 0; k < 4; ++k) {
        int a = min(max(e[k], 0), BSEG - 1);
        int b = (k == 3) ? (last ? BSEG : min(max(e[4], 0), BSEG - 1))
                         : min(max(e[k + 1], 0), BSEG - 1);
        int pos = i0 + k + 1; if (pos > N) pos = N;
        for (int s = a + 1; s <= b; ++s) start[s] = pos;
    }
}

// ---- k2: main streaming sum (full occupancy).
__global__ __launch_bounds__(MB_THREADS, 8)
void pool_main(const float4* __restrict__ x4, const int* __restrict__ start,
               float* __restrict__ partial /* [MB_BLOCKS][BD] */)
{
    __shared__ float lds_sum[BSEG][D];
    __shared__ int   lds_st[BSEG + 1];

    const int tid = threadIdx.x;
    for (int i = tid; i < BD; i += MB_THREADS) ((float*)lds_sum)[i] = 0.0f;
    if (tid <= BSEG) lds_st[tid] = start[tid];
    __syncthreads();

    const int gtid = blockIdx.x * MB_THREADS + tid;
    const int col4 = tid & (D4 - 1);      // constant column (GSTRIDE ≡ 0 mod 32)
    const int lane = tid & 63;

    #pragma unroll 1
    for (int s = 0; s < BSEG; ++s) {
        const int i0 = lds_st[s] * D4 + gtid;
        const int e1 = lds_st[s + 1] * D4;          // max 64M, fits int
        float4 a = make_float4(0.f, 0.f, 0.f, 0.f);
        for (int i = i0; i < e1; i += GSTRIDE) {
            float4 v = x4[i];
            a.x += v.x; a.y += v.y; a.z += v.z; a.w += v.w;
        }
        // lanes l and l+32 hold the same column: fold within wave
        a.x += __shfl_down(a.x, 32);
        a.y += __shfl_down(a.y, 32);
        a.z += __shfl_down(a.z, 32);
        a.w += __shfl_down(a.w, 32);
        if (lane < 32) {
            atomicAdd(&lds_sum[s][col4 * 4 + 0], a.x);
            atomicAdd(&lds_sum[s][col4 * 4 + 1], a.y);
            atomicAdd(&lds_sum[s][col4 * 4 + 2], a.z);
            atomicAdd(&lds_sum[s][col4 * 4 + 3], a.w);
        }
    }
    __syncthreads();

    // BD floats = 512 float4s: first 512 threads store one float4 each
    if (tid < BD / 4) {
        float4* pp = (float4*)(partial + (long)blockIdx.x * BD);
        pp[tid] = ((const float4*)lds_sum)[tid];
    }
}

// ---- k3: reduce partials.  32768 threads = 2048 cols x 16 row-groups.
__global__ __launch_bounds__(256)
void stage2_kernel(const float* __restrict__ partial, float* __restrict__ sums)
{
    int g   = blockIdx.x * 256 + threadIdx.x;   // 0..32767
    int col = g & (BD - 1);
    int grp = g >> 11;                          // 0..15
    const int rows = MB_BLOCKS / 16;            // 32
    int r0 = grp * rows;
    float s = 0.f;
    for (int k = 0; k < rows; ++k)
        s += partial[(r0 + k) * BD + col];
    atomicAdd(&sums[col], s);
}

// ---- k4: divide by counts derived from boundaries.
__global__ __launch_bounds__(256)
void div_kernel(const float* __restrict__ sums, const int* __restrict__ start,
                float* __restrict__ out)
{
    int i = blockIdx.x * 256 + threadIdx.x;
    if (i < BD) {
        int s = i >> 7;
        float c = (float)(start[s + 1] - start[s]);
        out[i] = sums[i] / fmaxf(c, 1.0f);
    }
}

// ---------------- fallback (round-1 kernel) if ws is too small --------------
__global__ __launch_bounds__(256)
void pool_sum_fb(const float* __restrict__ x, const int* __restrict__ batch,
                 float* __restrict__ sums, float* __restrict__ counts,
                 int N, int nblocks)
{
    __shared__ float lds_sum[BSEG][D];
    __shared__ float lds_cnt[BSEG];
    const int tid = threadIdx.x;
    for (int i = tid; i < BD; i += 256) ((float*)lds_sum)[i] = 0.0f;
    if (tid < BSEG) lds_cnt[tid] = 0.0f;
    __syncthreads();

    const int chunk = (N + nblocks - 1) / nblocks;
    const int r0 = blockIdx.x * chunk;
    int r1 = r0 + chunk; if (r1 > N) r1 = N;
    const int col4 = tid & (D4 - 1);
    const int rlane = tid >> 5;
    const float4* x4 = (const float4*)x;

    float4 acc = make_float4(0.f, 0.f, 0.f, 0.f);
    int cnt = 0, cur = -1;
    for (int r = r0 + rlane; r < r1; r += 8) {
        int seg = batch[r];
        if (seg != cur) {
            if (cur >= 0) {
                atomicAdd(&lds_sum[cur][col4 * 4 + 0], acc.x);
                atomicAdd(&lds_sum[cur][col4 * 4 + 1], acc.y);
                atomicAdd(&lds_sum[cur][col4 * 4 + 2], acc.z);
                atomicAdd(&lds_sum[cur][col4 * 4 + 3], acc.w);
                if (col4 == 0) atomicAdd(&lds_cnt[cur], (float)cnt);
            }
            acc = make_float4(0.f, 0.f, 0.f, 0.f); cnt = 0;
            cur = (seg >= 0 && seg < BSEG) ? seg : -1;
        }
        if (cur >= 0) {
            float4 v = x4[(long)r * D4 + col4];
            acc.x += v.x; acc.y += v.y; acc.z += v.z; acc.w += v.w; cnt++;
        }
    }
    if (cur >= 0) {
        atomicAdd(&lds_sum[cur][col4 * 4 + 0], acc.x);
        atomicAdd(&lds_sum[cur][col4 * 4 + 1], acc.y);
        atomicAdd(&lds_sum[cur][col4 * 4 + 2], acc.z);
        atomicAdd(&lds_sum[cur][col4 * 4 + 3], acc.w);
        if (col4 == 0) atomicAdd(&lds_cnt[cur], (float)cnt);
    }
    __syncthreads();
    for (int i = tid; i < BD; i += 256) {
        float v = ((float*)lds_sum)[i];
        if (v != 0.0f) atomicAdd(&sums[i], v);
    }
    if (tid < BSEG) {
        float c = lds_cnt[tid];
        if (c != 0.0f) atomicAdd(&counts[tid], c);
    }
}

__global__ __launch_bounds__(256)
void div_fb(const float* __restrict__ sums, const float* __restrict__ counts,
            float* __restrict__ out)
{
    int i = blockIdx.x * 256 + threadIdx.x;
    if (i < BD) out[i] = sums[i] / fmaxf(counts[i >> 7], 1.0f);
}

// ---------------------------------------------------------------------------
extern "C" void kernel_launch(void* const* d_in, const int* in_sizes, int n_in,
                              void* d_out, int out_size, void* d_ws, size_t ws_size,
                              hipStream_t stream)
{
    const float* x     = (const float*)d_in[0];
    const int*   batch = (const int*)d_in[1];
    const int    N     = in_sizes[1];

    // ws layout: [start: 32 ints][sums: BD floats][partial: MB_BLOCKS*BD floats]
    int*   start   = (int*)d_ws;
    float* sums    = (float*)d_ws + 32;
    float* partial = (float*)d_ws + 32 + BD;
    const size_t need = (size_t)(32 + BD + (size_t)MB_BLOCKS * BD) * sizeof(float);

    if (ws_size >= need) {
        hipMemsetAsync(sums, 0, BD * sizeof(float), stream);
        boundary_kernel<<<(N / 4 + 255) / 256, 256, 0, stream>>>(batch, N, start);
        pool_main<<<MB_BLOCKS, MB_THREADS, 0, stream>>>((const float4*)x, start, partial);
        stage2_kernel<<<128, 256, 0, stream>>>(partial, sums);
        div_kernel<<<8, 256, 0, stream>>>(sums, start, (float*)d_out);
    } else {
        float* fsums   = (float*)d_ws;
        float* fcounts = fsums + BD;
        hipMemsetAsync(d_ws, 0, (BD + BSEG) * sizeof(float), stream);
        pool_sum_fb<<<2048, 256, 0, stream>>>(x, batch, fsums, fcounts, N, 2048);
        div_fb<<<8, 256, 0, stream>>>(fsums, fcounts, (float*)d_out);
    }
}